// Round 8
// baseline (217.513 us; speedup 1.0000x reference)
//
#include <hip/hip_runtime.h>

typedef float vf2 __attribute__((ext_vector_type(2)));

// ---------------------------------------------------------------------------
// helpers: cross-lane primitives (ALL VALU; DS only for the chain bpermutes)
// ---------------------------------------------------------------------------
__device__ __forceinline__ int   f2i(float x){ return __builtin_bit_cast(int, x); }
__device__ __forceinline__ float i2f(int x)  { return __builtin_bit_cast(float, x); }

template<int CTRL>
__device__ __forceinline__ float dppf(float x){
    return i2f(__builtin_amdgcn_mov_dpp(f2i(x), CTRL, 0xF, 0xF, true));
}
// xor32 via permlane32_swap, convention-immune: self-swap returns the two
// 32-half duplicates in some order; partner = r0 + r1 - own.
__device__ __forceinline__ float xor32f(float x){
    unsigned ux = __builtin_bit_cast(unsigned, x);
    auto r = __builtin_amdgcn_permlane32_swap(ux, ux, false, false);
    float a = __builtin_bit_cast(float, (unsigned)r[0]);
    float b = __builtin_bit_cast(float, (unsigned)r[1]);
    return (a + b) - x;
}
// pair-sum over lane-bit 5: x + partner  (convention-immune)
__device__ __forceinline__ float sum32(float x){
    unsigned ux = __builtin_bit_cast(unsigned, x);
    auto r = __builtin_amdgcn_permlane32_swap(ux, ux, false, false);
    float a = __builtin_bit_cast(float, (unsigned)r[0]);
    float b = __builtin_bit_cast(float, (unsigned)r[1]);
    return a + b;
}
#if defined(__has_builtin)
#if __has_builtin(__builtin_amdgcn_permlane16_swap)
#define HAVE_PL16 1
#endif
#endif
__device__ __forceinline__ float xor16f(float x){
#ifdef HAVE_PL16
    unsigned ux = __builtin_bit_cast(unsigned, x);
    auto r = __builtin_amdgcn_permlane16_swap(ux, ux, false, false);
    float a = __builtin_bit_cast(float, (unsigned)r[0]);
    float b = __builtin_bit_cast(float, (unsigned)r[1]);
    return (a + b) - x;
#else
    return dppf<0x140>(dppf<0x141>(x));   // row_mirror(xor15) ∘ half_mirror(xor7) = xor8? no—fallback unused on gfx950
#endif
}
// pair-sum over lane-bit 4
__device__ __forceinline__ float sum16(float x){
#ifdef HAVE_PL16
    unsigned ux = __builtin_bit_cast(unsigned, x);
    auto r = __builtin_amdgcn_permlane16_swap(ux, ux, false, false);
    float a = __builtin_bit_cast(float, (unsigned)r[0]);
    float b = __builtin_bit_cast(float, (unsigned)r[1]);
    return a + b;
#else
    return x + xor16f(x);
#endif
}
// lane-xor on bit B — all VALU:
//  B=0: quad_perm[1,0,3,2]      (xor1)
//  B=1: quad_perm[2,3,0,1]      (xor2)
//  B=2: half_mirror∘quad_rev    (xor7 ∘ xor3 = xor4)
//  B=3: row_ror:8               (xor8)
//  B=4: permlane16_swap         (xor16)
//  B=5: permlane32_swap         (xor32)
template<int B>
__device__ __forceinline__ float lx(float x){
    if constexpr      (B == 0) return dppf<0xB1>(x);
    else if constexpr (B == 1) return dppf<0x4E>(x);
    else if constexpr (B == 2) return dppf<0x141>(dppf<0x1B>(x));
    else if constexpr (B == 3) return dppf<0x128>(x);
    else if constexpr (B == 4) return xor16f(x);
    else                       return xor32f(x);
}

// ---------------------------------------------------------------------------
// prep: build 60 fused gate matrices U = RZ*RY*RX from q_params (f32)
// ---------------------------------------------------------------------------
__global__ void k_prep(const float* __restrict__ qp, float* __restrict__ ws)
{
    int t = threadIdx.x;
    if (t >= 60) return;
    int l = t / 10;
    float tx = 0.5f * qp[t*3 + 0];
    float ty = 0.5f * qp[t*3 + 1];
    float tz = 0.5f * qp[t*3 + 2];
    float cx = cosf(tx), sx = sinf(tx);
    float cy = cosf(ty), sy = sinf(ty);
    float cz, sz;
    if (l == 5) { cz = 1.0f; sz = 0.0f; }   // final RZ commutes with Z readout
    else        { cz = cosf(tz); sz = sinf(tz); }
    float m00r =  cy*cx, m00i =  sy*sx;
    float m01r = -sy*cx, m01i = -cy*sx;
    float m10r =  sy*cx, m10i = -cy*sx;
    float m11r =  cy*cx, m11i = -sy*sx;
    float* U = ws + t*8;
    U[0] = m00r*cz + m00i*sz;  U[1] = m00i*cz - m00r*sz;
    U[2] = m01r*cz + m01i*sz;  U[3] = m01i*cz - m01r*sz;
    U[4] = m10r*cz - m10i*sz;  U[5] = m10i*cz + m10r*sz;
    U[6] = m11r*cz - m11i*sz;  U[7] = m11i*cz + m11r*sz;
}

// ---------------------------------------------------------------------------
// quantum sim: 1 wave = 1 sample; qubit q<6 -> lane bit q, q>=6 -> reg bit q-6
// state: 16 complex amps packed as vf2 pr[8], pi[8]  (pack k = regs 2k, 2k+1)
// ---------------------------------------------------------------------------

// composed CNOT chain CNOT(0,1)..CNOT(8,9): lane gather + reg cycle-chase
__device__ __forceinline__ void chainP(vf2 (&a)[8], int baddr, bool lpar)
{
    #pragma unroll
    for (int k = 0; k < 8; k++) {      // conditional intra-pack swap (^1 on reg)
        vf2 v  = a[k];
        vf2 sw = __builtin_shufflevector(v, v, 1, 0);
        a[k] = lpar ? sw : v;
    }
    auto BPf = [&](float v){ return i2f(__builtin_amdgcn_ds_bpermute(baddr, f2i(v))); };
#define A_(r) a[(r)>>1][(r)&1]
    // reg map f cycles: {0},{8},(1,3,5,15),(2,6,10,14),(4,12),(7,9,11,13)
    A_(0) = BPf(A_(0));
    A_(8) = BPf(A_(8));
    { float t=A_(1); A_(1)=BPf(A_(3));  A_(3)=BPf(A_(5));  A_(5)=BPf(A_(15)); A_(15)=BPf(t); }
    { float t=A_(2); A_(2)=BPf(A_(6));  A_(6)=BPf(A_(10)); A_(10)=BPf(A_(14)); A_(14)=BPf(t); }
    { float t=A_(4); A_(4)=BPf(A_(12)); A_(12)=BPf(t); }
    { float t=A_(7); A_(7)=BPf(A_(9));  A_(9)=BPf(A_(11)); A_(11)=BPf(A_(13)); A_(13)=BPf(t); }
#undef A_
}

// gate on lane bit B (B in {0,1,2,3}: direct partner via DPP)
template<int B>
__device__ __forceinline__ void lane_gateP(vf2 (&pr)[8], vf2 (&pi)[8],
                                           const float* __restrict__ U, int lane)
{
    float u00r=U[0], u00i=U[1], u01r=U[2], u01i=U[3];
    float u10r=U[4], u10i=U[5], u11r=U[6], u11i=U[7];
    bool hi = (lane >> B) & 1;
    float msr = hi ? u11r : u00r, msi = hi ? u11i : u00i;
    float mor = hi ? u10r : u01r, moi = hi ? u10i : u01i;
    #pragma unroll
    for (int k = 0; k < 8; k++){
        vf2 orr, oii;
        orr.x = lx<B>(pr[k].x);  orr.y = lx<B>(pr[k].y);
        oii.x = lx<B>(pi[k].x);  oii.y = lx<B>(pi[k].y);
        vf2 nr = msr*pr[k] - msi*pi[k] + mor*orr - moi*oii;
        vf2 ni = msr*pi[k] + msi*pr[k] + mor*oii + moi*orr;
        pr[k] = nr; pi[k] = ni;
    }
}

// gate on lane bit B (B in {4,5}): pair-sum form, convention-immune.
// S = a + partner; new = (ms-mo)*a + mo*S.
template<int B>
__device__ __forceinline__ void lane_gateS(vf2 (&pr)[8], vf2 (&pi)[8],
                                           const float* __restrict__ U, int lane)
{
    float u00r=U[0], u00i=U[1], u01r=U[2], u01i=U[3];
    float u10r=U[4], u10i=U[5], u11r=U[6], u11i=U[7];
    bool hi = (lane >> B) & 1;
    float msr = hi ? u11r : u00r, msi = hi ? u11i : u00i;
    float mor = hi ? u10r : u01r, moi = hi ? u10i : u01i;
    float dsr = msr - mor, dsi = msi - moi;
    #pragma unroll
    for (int k = 0; k < 8; k++){
        vf2 Sr, Si;
        if constexpr (B == 4) {
            Sr.x = sum16(pr[k].x);  Sr.y = sum16(pr[k].y);
            Si.x = sum16(pi[k].x);  Si.y = sum16(pi[k].y);
        } else {
            Sr.x = sum32(pr[k].x);  Sr.y = sum32(pr[k].y);
            Si.x = sum32(pi[k].x);  Si.y = sum32(pi[k].y);
        }
        vf2 nr = dsr*pr[k] - dsi*pi[k] + mor*Sr - moi*Si;
        vf2 ni = dsr*pi[k] + dsi*pr[k] + mor*Si + moi*Sr;
        pr[k] = nr; pi[k] = ni;
    }
}

// reg-bit gate with partner in a different pack (qubits 7,8,9 -> M2 = 1,2,4)
template<int M2>
__device__ __forceinline__ void reg_gateP(vf2 (&pr)[8], vf2 (&pi)[8],
                                          const float* __restrict__ U)
{
    float u00r=U[0], u00i=U[1], u01r=U[2], u01i=U[3];
    float u10r=U[4], u10i=U[5], u11r=U[6], u11i=U[7];
    #pragma unroll
    for (int k = 0; k < 8; k++) if (!(k & M2)) {
        const int k2 = k | M2;
        vf2 A0r=pr[k], A0i=pi[k], A1r=pr[k2], A1i=pi[k2];
        pr[k]  = u00r*A0r - u00i*A0i + u01r*A1r - u01i*A1i;
        pi[k]  = u00r*A0i + u00i*A0r + u01r*A1i + u01i*A1r;
        pr[k2] = u10r*A0r - u10i*A0i + u11r*A1r - u11i*A1i;
        pi[k2] = u10r*A0i + u10i*A0r + u11r*A1i + u11i*A1r;
    }
}

template<int B>
__device__ __forceinline__ float st_signed(float v, int lane){
    float t = lx<B>(v);
    return ((lane >> B) & 1) ? (t - v) : (v - t);
}
template<int B>
__device__ __forceinline__ float st_plain(float v){
    if constexpr (B == 4) return sum16(v);
    else if constexpr (B == 5) return sum32(v);
    else return v + lx<B>(v);
}

template<int I>
__device__ __forceinline__ float z_mixed(float S, int lane){
    float v = st_signed<0>(S, lane);
    if constexpr (I >= 1) v = st_signed<1>(v, lane); else v = st_plain<1>(v);
    if constexpr (I >= 2) v = st_signed<2>(v, lane); else v = st_plain<2>(v);
    if constexpr (I >= 3) v = st_signed<3>(v, lane); else v = st_plain<3>(v);
    if constexpr (I >= 4) v = st_signed<4>(v, lane); else v = st_plain<4>(v);
    if constexpr (I >= 5) v = st_signed<5>(v, lane); else v = st_plain<5>(v);
    return v;
}

__global__ __launch_bounds__(256)
__attribute__((amdgpu_waves_per_eu(5, 8)))
void k_qsim(
        const float* __restrict__ x,
        const float* __restrict__ W1, const float* __restrict__ b1,
        const float* __restrict__ W2, const float* __restrict__ b2,
        const float* __restrict__ ws,
        const float* __restrict__ W3, const float* __restrict__ b3,
        const float* __restrict__ W4, const float* __restrict__ b4,
        float* __restrict__ out)
{
    const int lane = threadIdx.x & 63;
    int wid = (blockIdx.x * 256 + threadIdx.x) >> 6;
    const int s = __builtin_amdgcn_readfirstlane(wid);

    // Opaque zero in a VGPR: gate-matrix loads become VECTOR loads (vmcnt),
    // decoupled from the chain's ds_bpermute waits (lgkmcnt).
    int vzero;
    asm("v_mov_b32 %0, 0" : "=v"(vzero));
    const float* __restrict__ wsv = ws + vzero;

    // ---- fused front MLP: x(64) -> relu h(32) -> 10 angles -> cos/sin ------
    float cv[10], sv[10];
    {
        const float* xr  = x + s * 64;            // wave-uniform -> s_loads
        const int j = lane & 31;                  // lanes j and j+32 do row j
        const float* w1r = W1 + j * 64;
        float a = b1[j];
        #pragma unroll
        for (int k = 0; k < 64; k += 4) {
            float4 xv = *reinterpret_cast<const float4*>(xr + k);
            float4 wv = *reinterpret_cast<const float4*>(w1r + k);
            a = fmaf(wv.x, xv.x, a);
            a = fmaf(wv.y, xv.y, a);
            a = fmaf(wv.z, xv.z, a);
            a = fmaf(wv.w, xv.w, a);
        }
        float h = fmaxf(a, 0.0f);

        float tsel = 0.0f;
        #pragma unroll
        for (int i = 0; i < 10; i++) {
            float t = W2[i*32 + j] * h;
            t = st_plain<4>(t);  t = st_plain<3>(t);  t = st_plain<2>(t);
            t = st_plain<1>(t);  t = st_plain<0>(t);  // sum within 32-lane half
            t += b2[i];
            if (lane == i) tsel = t;               // lane i keeps angle i
        }
        float ang = tanhf(tsel) * 1.5707963267948966f;   // (tanh*pi)*0.5
        float sA, cA;
        __sincosf(ang, &sA, &cA);
        #pragma unroll
        for (int q = 0; q < 10; q++) {
            cv[q] = i2f(__builtin_amdgcn_readlane(f2i(cA), q));
            sv[q] = i2f(__builtin_amdgcn_readlane(f2i(sA), q));
        }
    }

    vf2 pr[8], pi[8];
#define ARr(r) pr[(r)>>1][(r)&1]
#define AIr(r) pi[(r)>>1][(r)&1]

    // ---- init: RY-encoding product state with layer-0 1q gates folded in ---
    {
        const float* U0 = wsv;
        float Lr, Li;
        {
            float v0r = U0[0]*cv[0] + U0[2]*sv[0], v0i = U0[1]*cv[0] + U0[3]*sv[0];
            float v1r = U0[4]*cv[0] + U0[6]*sv[0], v1i = U0[5]*cv[0] + U0[7]*sv[0];
            bool b = lane & 1;
            Lr = b ? v1r : v0r;  Li = b ? v1i : v0i;
        }
        #pragma unroll
        for (int q = 1; q < 6; q++) {
            const float* U = U0 + q*8;
            float v0r = U[0]*cv[q] + U[2]*sv[q], v0i = U[1]*cv[q] + U[3]*sv[q];
            float v1r = U[4]*cv[q] + U[6]*sv[q], v1i = U[5]*cv[q] + U[7]*sv[q];
            bool b = (lane >> q) & 1;
            float fr = b ? v1r : v0r, fi = b ? v1i : v0i;
            float nr = Lr*fr - Li*fi;
            float ni = Lr*fi + Li*fr;
            Lr = nr; Li = ni;
        }
        float vr[4][2], vi[4][2];
        #pragma unroll
        for (int q = 6; q < 10; q++) {
            const float* U = U0 + q*8;
            vr[q-6][0] = U[0]*cv[q] + U[2]*sv[q];  vi[q-6][0] = U[1]*cv[q] + U[3]*sv[q];
            vr[q-6][1] = U[4]*cv[q] + U[6]*sv[q];  vi[q-6][1] = U[5]*cv[q] + U[7]*sv[q];
        }
        float t67r[4], t67i[4], t89r[4], t89i[4];
        #pragma unroll
        for (int m = 0; m < 4; m++) {
            int b0 = m & 1, b1i = (m >> 1) & 1;
            t67r[m] = vr[0][b0]*vr[1][b1i] - vi[0][b0]*vi[1][b1i];
            t67i[m] = vr[0][b0]*vi[1][b1i] + vi[0][b0]*vr[1][b1i];
            t89r[m] = vr[2][b0]*vr[3][b1i] - vi[2][b0]*vi[3][b1i];
            t89i[m] = vr[2][b0]*vi[3][b1i] + vi[2][b0]*vr[3][b1i];
        }
        #pragma unroll
        for (int r = 0; r < 16; r++) {
            const int lo = r & 3, hi = r >> 2;
            float prr = t67r[lo]*t89r[hi] - t67i[lo]*t89i[hi];
            float pii = t67r[lo]*t89i[hi] + t67i[lo]*t89r[hi];
            ARr(r) = Lr*prr - Li*pii;
            AIr(r) = Lr*pii + Li*prr;
        }
    }

    const int  baddr = ((lane ^ (lane << 1)) & 63) << 2;
    const bool lpar  = __builtin_popcount(lane & 63) & 1;

    // ---- layers: chain(l-1) then gates(l), l = 1..5 (last chain folded) ----
    #pragma unroll 1
    for (int l = 1; l < 6; ++l) {
        chainP(pr, baddr, lpar);
        chainP(pi, baddr, lpar);
        const float* Ub = wsv + l * 80;
        lane_gateP<0>(pr, pi, Ub +  0, lane);
        lane_gateP<1>(pr, pi, Ub +  8, lane);
        lane_gateP<2>(pr, pi, Ub + 16, lane);
        lane_gateP<3>(pr, pi, Ub + 24, lane);
        lane_gateS<4>(pr, pi, Ub + 32, lane);
        lane_gateS<5>(pr, pi, Ub + 40, lane);
        // qubit 6 (reg bit 0): intra-pack 2x2 complex mix (scalar halves)
        {
            const float* U = Ub + 48;
            float u00r=U[0], u00i=U[1], u01r=U[2], u01i=U[3];
            float u10r=U[4], u10i=U[5], u11r=U[6], u11i=U[7];
            #pragma unroll
            for (int k = 0; k < 8; k++) {
                float a0r=pr[k].x, a0i=pi[k].x, a1r=pr[k].y, a1i=pi[k].y;
                pr[k].x = u00r*a0r - u00i*a0i + u01r*a1r - u01i*a1i;
                pi[k].x = u00r*a0i + u00i*a0r + u01r*a1i + u01i*a1r;
                pr[k].y = u10r*a0r - u10i*a0i + u11r*a1r - u11i*a1i;
                pi[k].y = u10r*a0i + u10i*a0r + u11r*a1i + u11i*a1r;
            }
        }
        reg_gateP<1>(pr, pi, Ub + 56);   // qubit 7
        reg_gateP<2>(pr, pi, Ub + 64);   // qubit 8
        reg_gateP<4>(pr, pi, Ub + 72);   // qubit 9
    }

    // ---- readout: z_i = sum p * (-1)^popcount(idx & prefix_mask_i) ---------
    float u[8], d[8];
    #pragma unroll
    for (int k = 0; k < 8; k++) {
        vf2 P = pr[k]*pr[k] + pi[k]*pi[k];
        u[k] = P.x + P.y;
        d[k] = P.x - P.y;
    }
    float S  = ((u[0]+u[1]) + (u[2]+u[3])) + ((u[4]+u[5]) + (u[6]+u[7]));
    float T0 = ((d[0]+d[1]) + (d[2]+d[3])) + ((d[4]+d[5]) + (d[6]+d[7]));
    float e0 = d[0]-d[1], e1 = d[2]-d[3], e2 = d[4]-d[5], e3 = d[6]-d[7];
    float T1 = (e0+e1) + (e2+e3);
    float f0 = e0-e1, f1 = e2-e3;
    float T2 = f0 + f1;
    float T3 = f0 - f1;

    float z[10];
    z[0] = z_mixed<0>(S, lane);
    z[1] = z_mixed<1>(S, lane);
    z[2] = z_mixed<2>(S, lane);
    z[3] = z_mixed<3>(S, lane);
    z[4] = z_mixed<4>(S, lane);
    z[5] = z_mixed<5>(S, lane);
    z[6] = z_mixed<5>(T0, lane);
    z[7] = z_mixed<5>(T1, lane);
    z[8] = z_mixed<5>(T2, lane);
    z[9] = z_mixed<5>(T3, lane);

    // ---- tail MLP: z -> relu(16) -> 2 (redundant per lane, lane0 stores) ---
    float acc0 = b4[0], acc1 = b4[1];
    #pragma unroll
    for (int j2 = 0; j2 < 16; j2++) {
        float a = b3[j2];
        #pragma unroll
        for (int q = 0; q < 10; q++) a = fmaf(W3[j2*10 + q], z[q], a);
        a = fmaxf(a, 0.0f);
        acc0 = fmaf(W4[j2],      a, acc0);
        acc1 = fmaf(W4[16 + j2], a, acc1);
    }
    if (lane == 0) {
        reinterpret_cast<float2*>(out)[s] = make_float2(acc0, acc1);
    }
#undef ARr
#undef AIr
}

extern "C" void kernel_launch(void* const* d_in, const int* in_sizes, int n_in,
                              void* d_out, int out_size, void* d_ws, size_t ws_size,
                              hipStream_t stream)
{
    (void)in_sizes; (void)n_in; (void)out_size; (void)ws_size;
    const float* x  = (const float*)d_in[0];
    const float* W1 = (const float*)d_in[1];
    const float* b1 = (const float*)d_in[2];
    const float* W2 = (const float*)d_in[3];
    const float* b2 = (const float*)d_in[4];
    const float* qp = (const float*)d_in[5];
    const float* W3 = (const float*)d_in[6];
    const float* b3 = (const float*)d_in[7];
    const float* W4 = (const float*)d_in[8];
    const float* b4 = (const float*)d_in[9];
    float* ws  = (float*)d_ws;
    float* out = (float*)d_out;

    k_prep<<<1, 64, 0, stream>>>(qp, ws);
    k_qsim<<<4096, 256, 0, stream>>>(x, W1, b1, W2, b2, ws, W3, b3, W4, b4, out);
}

// Round 10
// 190.455 us; speedup vs baseline: 1.1421x; 1.1421x over previous
//
#include <hip/hip_runtime.h>

typedef float vf2 __attribute__((ext_vector_type(2)));

// ---------------------------------------------------------------------------
// helpers: cross-lane primitives.
// Strategy (R9/R10): shuffles on lane bits 0..4 go to the DS pipe (ds_swizzle,
// 1 op, runs concurrent with VALU); only lane bit 5 uses permlane32 (VALU).
// ---------------------------------------------------------------------------
__device__ __forceinline__ int   f2i(float x){ return __builtin_bit_cast(int, x); }
__device__ __forceinline__ float i2f(int x)  { return __builtin_bit_cast(float, x); }

template<int PAT>
__device__ __forceinline__ float swzf(float x){
    return i2f(__builtin_amdgcn_ds_swizzle(f2i(x), PAT));
}
// xor32 via permlane32_swap, convention-immune: self-swap returns the two
// 32-half duplicates in some order; partner = r0 + r1 - own.
__device__ __forceinline__ float xor32f(float x){
    unsigned ux = __builtin_bit_cast(unsigned, x);
    auto r = __builtin_amdgcn_permlane32_swap(ux, ux, false, false);
    float a = __builtin_bit_cast(float, (unsigned)r[0]);
    float b = __builtin_bit_cast(float, (unsigned)r[1]);
    return (a + b) - x;
}
// pair-sum over lane-bit 5: x + partner  (convention-immune)
__device__ __forceinline__ float sum32(float x){
    unsigned ux = __builtin_bit_cast(unsigned, x);
    auto r = __builtin_amdgcn_permlane32_swap(ux, ux, false, false);
    float a = __builtin_bit_cast(float, (unsigned)r[0]);
    float b = __builtin_bit_cast(float, (unsigned)r[1]);
    return a + b;
}
// lane-xor on bit B: B<=4 -> ds_swizzle xor pattern (m<<10)|0x1F; B=5 -> VALU
template<int B>
__device__ __forceinline__ float lx(float x){
    if constexpr      (B == 0) return swzf<0x041F>(x);
    else if constexpr (B == 1) return swzf<0x081F>(x);
    else if constexpr (B == 2) return swzf<0x101F>(x);
    else if constexpr (B == 3) return swzf<0x201F>(x);
    else if constexpr (B == 4) return swzf<0x401F>(x);
    else                       return xor32f(x);
}

// ---------------------------------------------------------------------------
// prep: build 60 fused gate matrices U = RZ*RY*RX from q_params (f32)
// ---------------------------------------------------------------------------
__global__ void k_prep(const float* __restrict__ qp, float* __restrict__ ws)
{
    int t = threadIdx.x;
    if (t >= 60) return;
    int l = t / 10;
    float tx = 0.5f * qp[t*3 + 0];
    float ty = 0.5f * qp[t*3 + 1];
    float tz = 0.5f * qp[t*3 + 2];
    float cx = cosf(tx), sx = sinf(tx);
    float cy = cosf(ty), sy = sinf(ty);
    float cz, sz;
    if (l == 5) { cz = 1.0f; sz = 0.0f; }   // final RZ commutes with Z readout
    else        { cz = cosf(tz); sz = sinf(tz); }
    float m00r =  cy*cx, m00i =  sy*sx;
    float m01r = -sy*cx, m01i = -cy*sx;
    float m10r =  sy*cx, m10i = -cy*sx;
    float m11r =  cy*cx, m11i = -sy*sx;
    float* U = ws + t*8;
    U[0] = m00r*cz + m00i*sz;  U[1] = m00i*cz - m00r*sz;
    U[2] = m01r*cz + m01i*sz;  U[3] = m01i*cz - m01r*sz;
    U[4] = m10r*cz - m10i*sz;  U[5] = m10i*cz + m10r*sz;
    U[6] = m11r*cz - m11i*sz;  U[7] = m11i*cz + m11r*sz;
}

// ---------------------------------------------------------------------------
// quantum sim: 1 wave = 1 sample; qubit q<6 -> lane bit q, q>=6 -> reg bit q-6
// state: 16 complex amps packed as vf2 pr[8], pi[8]  (pack k = regs 2k, 2k+1)
// ---------------------------------------------------------------------------

// composed CNOT chain CNOT(0,1)..CNOT(8,9): lane gather + reg cycle-chase
__device__ __forceinline__ void chainP(vf2 (&a)[8], int baddr, bool lpar)
{
    #pragma unroll
    for (int k = 0; k < 8; k++) {      // conditional intra-pack swap (^1 on reg)
        vf2 v  = a[k];
        vf2 sw = __builtin_shufflevector(v, v, 1, 0);
        a[k] = lpar ? sw : v;
    }
    auto BPf = [&](float v){ return i2f(__builtin_amdgcn_ds_bpermute(baddr, f2i(v))); };
#define A_(r) a[(r)>>1][(r)&1]
    // reg map f cycles: {0},{8},(1,3,5,15),(2,6,10,14),(4,12),(7,9,11,13)
    A_(0) = BPf(A_(0));
    A_(8) = BPf(A_(8));
    { float t=A_(1); A_(1)=BPf(A_(3));  A_(3)=BPf(A_(5));  A_(5)=BPf(A_(15)); A_(15)=BPf(t); }
    { float t=A_(2); A_(2)=BPf(A_(6));  A_(6)=BPf(A_(10)); A_(10)=BPf(A_(14)); A_(14)=BPf(t); }
    { float t=A_(4); A_(4)=BPf(A_(12)); A_(12)=BPf(t); }
    { float t=A_(7); A_(7)=BPf(A_(9));  A_(9)=BPf(A_(11)); A_(11)=BPf(A_(13)); A_(13)=BPf(t); }
#undef A_
}

// gate on lane bit B (B in {0,1,2,3,4}: partner via ds_swizzle, DS pipe)
template<int B>
__device__ __forceinline__ void lane_gateP(vf2 (&pr)[8], vf2 (&pi)[8],
                                           const float* __restrict__ U, int lane)
{
    float u00r=U[0], u00i=U[1], u01r=U[2], u01i=U[3];
    float u10r=U[4], u10i=U[5], u11r=U[6], u11i=U[7];
    bool hi = (lane >> B) & 1;
    float msr = hi ? u11r : u00r, msi = hi ? u11i : u00i;
    float mor = hi ? u10r : u01r, moi = hi ? u10i : u01i;
    #pragma unroll
    for (int k = 0; k < 8; k++){
        vf2 orr, oii;
        orr.x = lx<B>(pr[k].x);  orr.y = lx<B>(pr[k].y);
        oii.x = lx<B>(pi[k].x);  oii.y = lx<B>(pi[k].y);
        vf2 nr = msr*pr[k] - msi*pi[k] + mor*orr - moi*oii;
        vf2 ni = msr*pi[k] + msi*pr[k] + mor*oii + moi*orr;
        pr[k] = nr; pi[k] = ni;
    }
}

// gate on lane bit 5: pair-sum form (permlane32), convention-immune.
// S = a + partner; new = (ms-mo)*a + mo*S.
__device__ __forceinline__ void lane_gateS5(vf2 (&pr)[8], vf2 (&pi)[8],
                                            const float* __restrict__ U, int lane)
{
    float u00r=U[0], u00i=U[1], u01r=U[2], u01i=U[3];
    float u10r=U[4], u10i=U[5], u11r=U[6], u11i=U[7];
    bool hi = (lane >> 5) & 1;
    float msr = hi ? u11r : u00r, msi = hi ? u11i : u00i;
    float mor = hi ? u10r : u01r, moi = hi ? u10i : u01i;
    float dsr = msr - mor, dsi = msi - moi;
    #pragma unroll
    for (int k = 0; k < 8; k++){
        vf2 Sr, Si;
        Sr.x = sum32(pr[k].x);  Sr.y = sum32(pr[k].y);
        Si.x = sum32(pi[k].x);  Si.y = sum32(pi[k].y);
        vf2 nr = dsr*pr[k] - dsi*pi[k] + mor*Sr - moi*Si;
        vf2 ni = dsr*pi[k] + dsi*pr[k] + mor*Si + moi*Sr;
        pr[k] = nr; pi[k] = ni;
    }
}

// reg-bit gate with partner in a different pack (qubits 7,8,9 -> M2 = 1,2,4)
template<int M2>
__device__ __forceinline__ void reg_gateP(vf2 (&pr)[8], vf2 (&pi)[8],
                                          const float* __restrict__ U)
{
    float u00r=U[0], u00i=U[1], u01r=U[2], u01i=U[3];
    float u10r=U[4], u10i=U[5], u11r=U[6], u11i=U[7];
    #pragma unroll
    for (int k = 0; k < 8; k++) if (!(k & M2)) {
        const int k2 = k | M2;
        vf2 A0r=pr[k], A0i=pi[k], A1r=pr[k2], A1i=pi[k2];
        pr[k]  = u00r*A0r - u00i*A0i + u01r*A1r - u01i*A1i;
        pi[k]  = u00r*A0i + u00i*A0r + u01r*A1i + u01i*A1r;
        pr[k2] = u10r*A0r - u10i*A0i + u11r*A1r - u11i*A1i;
        pi[k2] = u10r*A0i + u10i*A0r + u11r*A1i + u11i*A1r;
    }
}

template<int B>
__device__ __forceinline__ float st_signed(float v, int lane){
    float t = lx<B>(v);
    return ((lane >> B) & 1) ? (t - v) : (v - t);
}
template<int B>
__device__ __forceinline__ float st_plain(float v){
    if constexpr (B == 5) return sum32(v);
    else return v + lx<B>(v);
}

template<int I>
__device__ __forceinline__ float z_mixed(float S, int lane){
    float v = st_signed<0>(S, lane);
    if constexpr (I >= 1) v = st_signed<1>(v, lane); else v = st_plain<1>(v);
    if constexpr (I >= 2) v = st_signed<2>(v, lane); else v = st_plain<2>(v);
    if constexpr (I >= 3) v = st_signed<3>(v, lane); else v = st_plain<3>(v);
    if constexpr (I >= 4) v = st_signed<4>(v, lane); else v = st_plain<4>(v);
    if constexpr (I >= 5) v = st_signed<5>(v, lane); else v = st_plain<5>(v);
    return v;
}

__global__ __launch_bounds__(256)
__attribute__((amdgpu_waves_per_eu(5, 8)))
void k_qsim(
        const float* __restrict__ x,
        const float* __restrict__ W1, const float* __restrict__ b1,
        const float* __restrict__ W2, const float* __restrict__ b2,
        const float* __restrict__ ws,
        const float* __restrict__ W3, const float* __restrict__ b3,
        const float* __restrict__ W4, const float* __restrict__ b4,
        float* __restrict__ out)
{
    const int lane = threadIdx.x & 63;
    int wid = (blockIdx.x * 256 + threadIdx.x) >> 6;
    const int s = __builtin_amdgcn_readfirstlane(wid);

    // ---- fused front MLP: x(64) -> relu h(32) -> 10 angles -> cos/sin ------
    float cv[10], sv[10];
    {
        const float* xr  = x + s * 64;            // wave-uniform -> s_loads
        const int j = lane & 31;                  // lanes j and j+32 do row j
        const float* w1r = W1 + j * 64;
        float a = b1[j];
        #pragma unroll
        for (int k = 0; k < 64; k += 4) {
            float4 xv = *reinterpret_cast<const float4*>(xr + k);
            float4 wv = *reinterpret_cast<const float4*>(w1r + k);
            a = fmaf(wv.x, xv.x, a);
            a = fmaf(wv.y, xv.y, a);
            a = fmaf(wv.z, xv.z, a);
            a = fmaf(wv.w, xv.w, a);
        }
        float h = fmaxf(a, 0.0f);

        float tsel = 0.0f;
        #pragma unroll
        for (int i = 0; i < 10; i++) {
            float t = W2[i*32 + j] * h;
            t = st_plain<4>(t);  t = st_plain<3>(t);  t = st_plain<2>(t);
            t = st_plain<1>(t);  t = st_plain<0>(t);  // sum within 32-lane half
            t += b2[i];
            if (lane == i) tsel = t;               // lane i keeps angle i
        }
        float ang = tanhf(tsel) * 1.5707963267948966f;   // (tanh*pi)*0.5
        float sA, cA;
        __sincosf(ang, &sA, &cA);
        #pragma unroll
        for (int q = 0; q < 10; q++) {
            cv[q] = i2f(__builtin_amdgcn_readlane(f2i(cA), q));
            sv[q] = i2f(__builtin_amdgcn_readlane(f2i(sA), q));
        }
    }

    vf2 pr[8], pi[8];
#define ARr(r) pr[(r)>>1][(r)&1]
#define AIr(r) pi[(r)>>1][(r)&1]

    // ---- init: RY-encoding product state with layer-0 1q gates folded in ---
    {
        const float* U0 = ws;
        float Lr, Li;
        {
            float v0r = U0[0]*cv[0] + U0[2]*sv[0], v0i = U0[1]*cv[0] + U0[3]*sv[0];
            float v1r = U0[4]*cv[0] + U0[6]*sv[0], v1i = U0[5]*cv[0] + U0[7]*sv[0];
            bool b = lane & 1;
            Lr = b ? v1r : v0r;  Li = b ? v1i : v0i;
        }
        #pragma unroll
        for (int q = 1; q < 6; q++) {
            const float* U = U0 + q*8;
            float v0r = U[0]*cv[q] + U[2]*sv[q], v0i = U[1]*cv[q] + U[3]*sv[q];
            float v1r = U[4]*cv[q] + U[6]*sv[q], v1i = U[5]*cv[q] + U[7]*sv[q];
            bool b = (lane >> q) & 1;
            float fr = b ? v1r : v0r, fi = b ? v1i : v0i;
            float nr = Lr*fr - Li*fi;
            float ni = Lr*fi + Li*fr;
            Lr = nr; Li = ni;
        }
        float vr[4][2], vi[4][2];
        #pragma unroll
        for (int q = 6; q < 10; q++) {
            const float* U = U0 + q*8;
            vr[q-6][0] = U[0]*cv[q] + U[2]*sv[q];  vi[q-6][0] = U[1]*cv[q] + U[3]*sv[q];
            vr[q-6][1] = U[4]*cv[q] + U[6]*sv[q];  vi[q-6][1] = U[5]*cv[q] + U[7]*sv[q];
        }
        float t67r[4], t67i[4], t89r[4], t89i[4];
        #pragma unroll
        for (int m = 0; m < 4; m++) {
            int b0 = m & 1, b1i = (m >> 1) & 1;
            t67r[m] = vr[0][b0]*vr[1][b1i] - vi[0][b0]*vi[1][b1i];
            t67i[m] = vr[0][b0]*vi[1][b1i] + vi[0][b0]*vr[1][b1i];
            t89r[m] = vr[2][b0]*vr[3][b1i] - vi[2][b0]*vi[3][b1i];
            t89i[m] = vr[2][b0]*vi[3][b1i] + vi[2][b0]*vr[3][b1i];
        }
        #pragma unroll
        for (int r = 0; r < 16; r++) {
            const int lo = r & 3, hi = r >> 2;
            float prr = t67r[lo]*t89r[hi] - t67i[lo]*t89i[hi];
            float pii = t67r[lo]*t89i[hi] + t67i[lo]*t89r[hi];
            ARr(r) = Lr*prr - Li*pii;
            AIr(r) = Lr*pii + Li*prr;
        }
    }

    const int  baddr = ((lane ^ (lane << 1)) & 63) << 2;
    const bool lpar  = __builtin_popcount(lane & 63) & 1;

    // ---- layers: chain(l-1) then gates(l), l = 1..5 (last chain folded) ----
    #pragma unroll 1
    for (int l = 1; l < 6; ++l) {
        chainP(pr, baddr, lpar);
        chainP(pi, baddr, lpar);
        const float* Ub = ws + l * 80;
        lane_gateP<0>(pr, pi, Ub +  0, lane);
        lane_gateP<1>(pr, pi, Ub +  8, lane);
        lane_gateP<2>(pr, pi, Ub + 16, lane);
        lane_gateP<3>(pr, pi, Ub + 24, lane);
        lane_gateP<4>(pr, pi, Ub + 32, lane);
        lane_gateS5  (pr, pi, Ub + 40, lane);
        // qubit 6 (reg bit 0): intra-pack 2x2 complex mix (scalar halves)
        {
            const float* U = Ub + 48;
            float u00r=U[0], u00i=U[1], u01r=U[2], u01i=U[3];
            float u10r=U[4], u10i=U[5], u11r=U[6], u11i=U[7];
            #pragma unroll
            for (int k = 0; k < 8; k++) {
                float a0r=pr[k].x, a0i=pi[k].x, a1r=pr[k].y, a1i=pi[k].y;
                pr[k].x = u00r*a0r - u00i*a0i + u01r*a1r - u01i*a1i;
                pi[k].x = u00r*a0i + u00i*a0r + u01r*a1i + u01i*a1r;
                pr[k].y = u10r*a0r - u10i*a0i + u11r*a1r - u11i*a1i;
                pi[k].y = u10r*a0i + u10i*a0r + u11r*a1i + u11i*a1r;
            }
        }
        reg_gateP<1>(pr, pi, Ub + 56);   // qubit 7
        reg_gateP<2>(pr, pi, Ub + 64);   // qubit 8
        reg_gateP<4>(pr, pi, Ub + 72);   // qubit 9
    }

    // ---- readout: z_i = sum p * (-1)^popcount(idx & prefix_mask_i) ---------
    float u[8], d[8];
    #pragma unroll
    for (int k = 0; k < 8; k++) {
        vf2 P = pr[k]*pr[k] + pi[k]*pi[k];
        u[k] = P.x + P.y;
        d[k] = P.x - P.y;
    }
    float S  = ((u[0]+u[1]) + (u[2]+u[3])) + ((u[4]+u[5]) + (u[6]+u[7]));
    float T0 = ((d[0]+d[1]) + (d[2]+d[3])) + ((d[4]+d[5]) + (d[6]+d[7]));
    float e0 = d[0]-d[1], e1 = d[2]-d[3], e2 = d[4]-d[5], e3 = d[6]-d[7];
    float T1 = (e0+e1) + (e2+e3);
    float f0 = e0-e1, f1 = e2-e3;
    float T2 = f0 + f1;
    float T3 = f0 - f1;

    float z[10];
    z[0] = z_mixed<0>(S, lane);
    z[1] = z_mixed<1>(S, lane);
    z[2] = z_mixed<2>(S, lane);
    z[3] = z_mixed<3>(S, lane);
    z[4] = z_mixed<4>(S, lane);
    z[5] = z_mixed<5>(S, lane);
    z[6] = z_mixed<5>(T0, lane);
    z[7] = z_mixed<5>(T1, lane);
    z[8] = z_mixed<5>(T2, lane);
    z[9] = z_mixed<5>(T3, lane);

    // ---- tail MLP: z -> relu(16) -> 2 (redundant per lane, lane0 stores) ---
    float acc0 = b4[0], acc1 = b4[1];
    #pragma unroll
    for (int j2 = 0; j2 < 16; j2++) {
        float a = b3[j2];
        #pragma unroll
        for (int q = 0; q < 10; q++) a = fmaf(W3[j2*10 + q], z[q], a);
        a = fmaxf(a, 0.0f);
        acc0 = fmaf(W4[j2],      a, acc0);
        acc1 = fmaf(W4[16 + j2], a, acc1);
    }
    if (lane == 0) {
        reinterpret_cast<float2*>(out)[s] = make_float2(acc0, acc1);
    }
#undef ARr
#undef AIr
}

extern "C" void kernel_launch(void* const* d_in, const int* in_sizes, int n_in,
                              void* d_out, int out_size, void* d_ws, size_t ws_size,
                              hipStream_t stream)
{
    (void)in_sizes; (void)n_in; (void)out_size; (void)ws_size;
    const float* x  = (const float*)d_in[0];
    const float* W1 = (const float*)d_in[1];
    const float* b1 = (const float*)d_in[2];
    const float* W2 = (const float*)d_in[3];
    const float* b2 = (const float*)d_in[4];
    const float* qp = (const float*)d_in[5];
    const float* W3 = (const float*)d_in[6];
    const float* b3 = (const float*)d_in[7];
    const float* W4 = (const float*)d_in[8];
    const float* b4 = (const float*)d_in[9];
    float* ws  = (float*)d_ws;
    float* out = (float*)d_out;

    k_prep<<<1, 64, 0, stream>>>(qp, ws);
    k_qsim<<<4096, 256, 0, stream>>>(x, W1, b1, W2, b2, ws, W3, b3, W4, b4, out);
}

// Round 11
// 163.059 us; speedup vs baseline: 1.3340x; 1.1680x over previous
//
#include <hip/hip_runtime.h>
#include <hip/hip_fp16.h>

typedef unsigned int u32;
typedef __half2 h2;

// ---------------------------------------------------------------------------
// helpers
// ---------------------------------------------------------------------------
__device__ __forceinline__ int   f2i(float x){ return __builtin_bit_cast(int, x); }
__device__ __forceinline__ float i2f(int x)  { return __builtin_bit_cast(float, x); }
__device__ __forceinline__ h2  b2h(u32 x){ return __builtin_bit_cast(h2, x); }
__device__ __forceinline__ u32 h2b(h2 x) { return __builtin_bit_cast(u32, x); }
__device__ __forceinline__ u32 rot16(u32 x){ return (x >> 16) | (x << 16); }

template<int PAT>
__device__ __forceinline__ float swzf(float x){
    return i2f(__builtin_amdgcn_ds_swizzle(f2i(x), PAT));
}
template<int PAT>
__device__ __forceinline__ u32 swzu(u32 x){
    return (u32)__builtin_amdgcn_ds_swizzle((int)x, PAT);
}
// f32 xor32 / sum via permlane32_swap (convention-immune)
__device__ __forceinline__ float xor32f(float x){
    unsigned ux = __builtin_bit_cast(unsigned, x);
    auto r = __builtin_amdgcn_permlane32_swap(ux, ux, false, false);
    float a = __builtin_bit_cast(float, (unsigned)r[0]);
    float b = __builtin_bit_cast(float, (unsigned)r[1]);
    return (a + b) - x;
}
__device__ __forceinline__ float sum32(float x){
    unsigned ux = __builtin_bit_cast(unsigned, x);
    auto r = __builtin_amdgcn_permlane32_swap(ux, ux, false, false);
    float a = __builtin_bit_cast(float, (unsigned)r[0]);
    float b = __builtin_bit_cast(float, (unsigned)r[1]);
    return a + b;
}
// h2 pair-sum over lane-bit 5: own + partner (halves move with the dword)
__device__ __forceinline__ u32 sum32h(u32 x){
    auto r = __builtin_amdgcn_permlane32_swap(x, x, false, false);
    return h2b(__hadd2(b2h((u32)r[0]), b2h((u32)r[1])));
}
// f32 lane-xor on bit B (for MLP reduce + readout butterflies)
template<int B>
__device__ __forceinline__ float lx(float x){
    if constexpr      (B == 0) return swzf<0x041F>(x);
    else if constexpr (B == 1) return swzf<0x081F>(x);
    else if constexpr (B == 2) return swzf<0x101F>(x);
    else if constexpr (B == 3) return swzf<0x201F>(x);
    else if constexpr (B == 4) return swzf<0x401F>(x);
    else                       return xor32f(x);
}
// u32 (h2-packed) lane-xor, bits 0..4 via ds_swizzle
template<int B>
__device__ __forceinline__ u32 lxu(u32 x){
    if constexpr      (B == 0) return swzu<0x041F>(x);
    else if constexpr (B == 1) return swzu<0x081F>(x);
    else if constexpr (B == 2) return swzu<0x101F>(x);
    else if constexpr (B == 3) return swzu<0x201F>(x);
    else                       return swzu<0x401F>(x);
}

// ---------------------------------------------------------------------------
// prep: f32 fused matrices (layer 0 / init) + h2-packed coeffs (layers 1..5)
// ws layout: [0..480) f32 U matrices; u32 words [480..880) h2 coefficients
// ---------------------------------------------------------------------------
__global__ void k_prep(const float* __restrict__ qp, float* __restrict__ ws)
{
    int t = threadIdx.x;
    if (t >= 60) return;
    int l = t / 10, q = t % 10;
    float tx = 0.5f * qp[t*3 + 0];
    float ty = 0.5f * qp[t*3 + 1];
    float tz = 0.5f * qp[t*3 + 2];
    float cx = cosf(tx), sx = sinf(tx);
    float cy = cosf(ty), sy = sinf(ty);
    float cz, sz;
    if (l == 5) { cz = 1.0f; sz = 0.0f; }   // final RZ commutes with Z readout
    else        { cz = cosf(tz); sz = sinf(tz); }
    float m00r =  cy*cx, m00i =  sy*sx;
    float m01r = -sy*cx, m01i = -cy*sx;
    float m10r =  sy*cx, m10i = -cy*sx;
    float m11r =  cy*cx, m11i = -sy*sx;
    float U[8];
    U[0] = m00r*cz + m00i*sz;  U[1] = m00i*cz - m00r*sz;
    U[2] = m01r*cz + m01i*sz;  U[3] = m01i*cz - m01r*sz;
    U[4] = m10r*cz - m10i*sz;  U[5] = m10i*cz + m10r*sz;
    U[6] = m11r*cz - m11i*sz;  U[7] = m11i*cz + m11r*sz;
    #pragma unroll
    for (int j = 0; j < 8; j++) ws[t*8 + j] = U[j];

    if (l >= 1) {
        u32* W = reinterpret_cast<u32*>(ws) + 480 + (l-1)*80 + q*8;
        auto pk2 = [](float a, float b){
            return __builtin_bit_cast(u32, __floats2half2_rn(a, b));
        };
        if (q == 9) {
            // intra-pack gate (amp bit3): mixed rows
            W[0] = pk2(U[0],  U[6]);   // Ar  = (u00r,  u11r)
            W[1] = pk2(-U[1], -U[7]);  // Br  = (-u00i, -u11i)
            W[2] = pk2(U[2],  U[4]);   // Cr  = (u01r,  u10r)
            W[3] = pk2(-U[3], -U[5]);  // Dr  = (-u01i, -u10i)
            W[4] = pk2(U[1],  U[7]);   // Ai2 = (u00i,  u11i)
            W[5] = pk2(U[3],  U[5]);   // Ci2 = (u01i,  u10i)
            W[6] = 0; W[7] = 0;
        } else {
            #pragma unroll
            for (int j = 0; j < 8; j++) W[j] = pk2(U[j], U[j]);
        }
    }
}

// ---------------------------------------------------------------------------
// quantum sim: 1 wave = 1 sample; qubit q<6 -> lane bit q, q>=6 -> amp bit q-6
// state: 16 complex amps in fp16: pack p (u32) holds (amp p, amp p+8); pr = re
// components, pi = im components.
// ---------------------------------------------------------------------------

// composed CNOT chain: lpar whole-reg pair swap, bpermute pack-permutation,
// static half-rotate where f(p) >= 8.  f(p) = (p ^ (p<<1)) & 15.
__device__ __forceinline__ void chainH(u32 (&a)[8], int baddr, bool lpar)
{
    #pragma unroll
    for (int k = 0; k < 4; k++) {
        u32 t0 = a[2*k], t1 = a[2*k+1];
        a[2*k]   = lpar ? t1 : t0;
        a[2*k+1] = lpar ? t0 : t1;
    }
    auto BP = [&](u32 v){ return (u32)__builtin_amdgcn_ds_bpermute(baddr, (int)v); };
    u32 n0 = BP(a[0]);
    u32 n1 = BP(a[3]);
    u32 n2 = BP(a[6]);
    u32 n3 = BP(a[5]);
    u32 n4 = rot16(BP(a[4]));
    u32 n5 = rot16(BP(a[7]));
    u32 n6 = rot16(BP(a[2]));
    u32 n7 = rot16(BP(a[1]));
    a[0]=n0; a[1]=n1; a[2]=n2; a[3]=n3; a[4]=n4; a[5]=n5; a[6]=n6; a[7]=n7;
}

// gate on lane bit B (0..4): partner via ds_swizzle on packed h2
template<int B>
__device__ __forceinline__ void lane_gateH(u32 (&pr)[8], u32 (&pi)[8],
                                           const u32* __restrict__ W, int lane)
{
    u32 w0=W[0], w1=W[1], w2=W[2], w3=W[3], w4=W[4], w5=W[5], w6=W[6], w7=W[7];
    bool hi = (lane >> B) & 1;
    h2 Msr = b2h(hi ? w6 : w0), Msi = b2h(hi ? w7 : w1);
    h2 Mor = b2h(hi ? w4 : w2), Moi = b2h(hi ? w5 : w3);
    h2 nMsi = __hneg2(Msi), nMoi = __hneg2(Moi);
    #pragma unroll
    for (int k = 0; k < 8; k++){
        h2 a  = b2h(pr[k]), b = b2h(pi[k]);
        h2 oa = b2h(lxu<B>(pr[k]));
        h2 ob = b2h(lxu<B>(pi[k]));
        h2 nr = __hfma2(Msr, a, __hfma2(nMsi, b, __hfma2(Mor, oa, __hmul2(nMoi, ob))));
        h2 ni = __hfma2(Msr, b, __hfma2(Msi, a, __hfma2(Mor, ob, __hmul2(Moi, oa))));
        pr[k] = h2b(nr); pi[k] = h2b(ni);
    }
}

// gate on lane bit 5: pair-sum form via permlane32 (convention-immune)
__device__ __forceinline__ void lane_gateS5H(u32 (&pr)[8], u32 (&pi)[8],
                                             const u32* __restrict__ W, int lane)
{
    u32 w0=W[0], w1=W[1], w2=W[2], w3=W[3], w4=W[4], w5=W[5], w6=W[6], w7=W[7];
    bool hi = (lane >> 5) & 1;
    h2 Msr = b2h(hi ? w6 : w0), Msi = b2h(hi ? w7 : w1);
    h2 Mor = b2h(hi ? w4 : w2), Moi = b2h(hi ? w5 : w3);
    h2 dsr = __hsub2(Msr, Mor), dsi = __hsub2(Msi, Moi);
    h2 ndsi = __hneg2(dsi), nMoi = __hneg2(Moi);
    #pragma unroll
    for (int k = 0; k < 8; k++){
        h2 a  = b2h(pr[k]), b = b2h(pi[k]);
        h2 Sr = b2h(sum32h(pr[k]));
        h2 Si = b2h(sum32h(pi[k]));
        h2 nr = __hfma2(dsr, a, __hfma2(ndsi, b, __hfma2(Mor, Sr, __hmul2(nMoi, Si))));
        h2 ni = __hfma2(dsr, b, __hfma2(dsi, a, __hfma2(Mor, Si, __hmul2(Moi, Sr))));
        pr[k] = h2b(nr); pi[k] = h2b(ni);
    }
}

// pack-pair gate (qubits 6,7,8 -> amp bits 0,1,2 -> pack-index M2 = 1,2,4)
template<int M2>
__device__ __forceinline__ void reg_gateH(u32 (&pr)[8], u32 (&pi)[8],
                                          const u32* __restrict__ W)
{
    h2 U00r=b2h(W[0]), U00i=b2h(W[1]), U01r=b2h(W[2]), U01i=b2h(W[3]);
    h2 U10r=b2h(W[4]), U10i=b2h(W[5]), U11r=b2h(W[6]), U11i=b2h(W[7]);
    h2 n00i=__hneg2(U00i), n01i=__hneg2(U01i), n10i=__hneg2(U10i), n11i=__hneg2(U11i);
    #pragma unroll
    for (int k = 0; k < 8; k++) if (!(k & M2)) {
        const int k2 = k | M2;
        h2 A0r=b2h(pr[k]), A0i=b2h(pi[k]), A1r=b2h(pr[k2]), A1i=b2h(pi[k2]);
        pr[k]  = h2b(__hfma2(U00r,A0r, __hfma2(n00i,A0i, __hfma2(U01r,A1r, __hmul2(n01i,A1i)))));
        pi[k]  = h2b(__hfma2(U00r,A0i, __hfma2(U00i,A0r, __hfma2(U01r,A1i, __hmul2(U01i,A1r)))));
        pr[k2] = h2b(__hfma2(U10r,A0r, __hfma2(n10i,A0i, __hfma2(U11r,A1r, __hmul2(n11i,A1i)))));
        pi[k2] = h2b(__hfma2(U10r,A0i, __hfma2(U10i,A0r, __hfma2(U11r,A1i, __hmul2(U11i,A1r)))));
    }
}

// intra-pack gate (qubit 9 -> amp bit 3 = the two halves of each pack)
__device__ __forceinline__ void q9_gateH(u32 (&pr)[8], u32 (&pi)[8],
                                         const u32* __restrict__ W)
{
    h2 Ar=b2h(W[0]), Br=b2h(W[1]), Cr=b2h(W[2]), Dr=b2h(W[3]);
    h2 Ai2=b2h(W[4]), Ci2=b2h(W[5]);
    #pragma unroll
    for (int k = 0; k < 8; k++){
        h2 a  = b2h(pr[k]),        b  = b2h(pi[k]);
        h2 as = b2h(rot16(pr[k])), bs = b2h(rot16(pi[k]));
        h2 nr = __hfma2(Ar,  a, __hfma2(Br, b, __hfma2(Cr,  as, __hmul2(Dr, bs))));
        h2 ni = __hfma2(Ai2, a, __hfma2(Ar, b, __hfma2(Ci2, as, __hmul2(Cr, bs))));
        pr[k] = h2b(nr); pi[k] = h2b(ni);
    }
}

template<int B>
__device__ __forceinline__ float st_signed(float v, int lane){
    float t = lx<B>(v);
    return ((lane >> B) & 1) ? (t - v) : (v - t);
}
template<int B>
__device__ __forceinline__ float st_plain(float v){
    if constexpr (B == 5) return sum32(v);
    else return v + lx<B>(v);
}
template<int I>
__device__ __forceinline__ float z_mixed(float S, int lane){
    float v = st_signed<0>(S, lane);
    if constexpr (I >= 1) v = st_signed<1>(v, lane); else v = st_plain<1>(v);
    if constexpr (I >= 2) v = st_signed<2>(v, lane); else v = st_plain<2>(v);
    if constexpr (I >= 3) v = st_signed<3>(v, lane); else v = st_plain<3>(v);
    if constexpr (I >= 4) v = st_signed<4>(v, lane); else v = st_plain<4>(v);
    if constexpr (I >= 5) v = st_signed<5>(v, lane); else v = st_plain<5>(v);
    return v;
}

__global__ __launch_bounds__(256)
__attribute__((amdgpu_waves_per_eu(5, 8)))
void k_qsim(
        const float* __restrict__ x,
        const float* __restrict__ W1, const float* __restrict__ b1,
        const float* __restrict__ W2, const float* __restrict__ b2,
        const float* __restrict__ ws,
        const float* __restrict__ W3, const float* __restrict__ b3,
        const float* __restrict__ W4, const float* __restrict__ b4,
        float* __restrict__ out)
{
    const int lane = threadIdx.x & 63;
    int wid = (blockIdx.x * 256 + threadIdx.x) >> 6;
    const int s = __builtin_amdgcn_readfirstlane(wid);

    // ---- fused front MLP: x(64) -> relu h(32) -> 10 angles -> cos/sin ------
    float cv[10], sv[10];
    {
        const float* xr  = x + s * 64;            // wave-uniform -> s_loads
        const int j = lane & 31;                  // lanes j and j+32 do row j
        const float* w1r = W1 + j * 64;
        float a = b1[j];
        #pragma unroll
        for (int k = 0; k < 64; k += 4) {
            float4 xv = *reinterpret_cast<const float4*>(xr + k);
            float4 wv = *reinterpret_cast<const float4*>(w1r + k);
            a = fmaf(wv.x, xv.x, a);
            a = fmaf(wv.y, xv.y, a);
            a = fmaf(wv.z, xv.z, a);
            a = fmaf(wv.w, xv.w, a);
        }
        float h = fmaxf(a, 0.0f);

        float tsel = 0.0f;
        #pragma unroll
        for (int i = 0; i < 10; i++) {
            float t = W2[i*32 + j] * h;
            t = st_plain<4>(t);  t = st_plain<3>(t);  t = st_plain<2>(t);
            t = st_plain<1>(t);  t = st_plain<0>(t);  // sum within 32-lane half
            t += b2[i];
            if (lane == i) tsel = t;               // lane i keeps angle i
        }
        float ang = tanhf(tsel) * 1.5707963267948966f;   // (tanh*pi)*0.5
        float sA, cA;
        __sincosf(ang, &sA, &cA);
        #pragma unroll
        for (int q = 0; q < 10; q++) {
            cv[q] = i2f(__builtin_amdgcn_readlane(f2i(cA), q));
            sv[q] = i2f(__builtin_amdgcn_readlane(f2i(sA), q));
        }
    }

    u32 pr[8], pi[8];   // pack p = (amp p, amp p+8), fp16 re / im

    // ---- init: product state with layer-0 gates folded in (f32 -> h2) ------
    {
        const float* U0 = ws;
        float Lr, Li;
        {
            float v0r = U0[0]*cv[0] + U0[2]*sv[0], v0i = U0[1]*cv[0] + U0[3]*sv[0];
            float v1r = U0[4]*cv[0] + U0[6]*sv[0], v1i = U0[5]*cv[0] + U0[7]*sv[0];
            bool b = lane & 1;
            Lr = b ? v1r : v0r;  Li = b ? v1i : v0i;
        }
        #pragma unroll
        for (int q = 1; q < 6; q++) {
            const float* U = U0 + q*8;
            float v0r = U[0]*cv[q] + U[2]*sv[q], v0i = U[1]*cv[q] + U[3]*sv[q];
            float v1r = U[4]*cv[q] + U[6]*sv[q], v1i = U[5]*cv[q] + U[7]*sv[q];
            bool b = (lane >> q) & 1;
            float fr = b ? v1r : v0r, fi = b ? v1i : v0i;
            float nr = Lr*fr - Li*fi;
            float ni = Lr*fi + Li*fr;
            Lr = nr; Li = ni;
        }
        float vr[4][2], vi[4][2];
        #pragma unroll
        for (int q = 6; q < 10; q++) {
            const float* U = U0 + q*8;
            vr[q-6][0] = U[0]*cv[q] + U[2]*sv[q];  vi[q-6][0] = U[1]*cv[q] + U[3]*sv[q];
            vr[q-6][1] = U[4]*cv[q] + U[6]*sv[q];  vi[q-6][1] = U[5]*cv[q] + U[7]*sv[q];
        }
        float t67r[4], t67i[4], t89r[4], t89i[4];
        #pragma unroll
        for (int m = 0; m < 4; m++) {
            int b0 = m & 1, b1i = (m >> 1) & 1;
            t67r[m] = vr[0][b0]*vr[1][b1i] - vi[0][b0]*vi[1][b1i];
            t67i[m] = vr[0][b0]*vi[1][b1i] + vi[0][b0]*vr[1][b1i];
            t89r[m] = vr[2][b0]*vr[3][b1i] - vi[2][b0]*vi[3][b1i];
            t89i[m] = vr[2][b0]*vi[3][b1i] + vi[2][b0]*vr[3][b1i];
        }
        #pragma unroll
        for (int p = 0; p < 8; p++) {
            const int lo = p & 3, h0 = p >> 2, h1 = h0 + 2;
            float prr0 = t67r[lo]*t89r[h0] - t67i[lo]*t89i[h0];
            float pii0 = t67r[lo]*t89i[h0] + t67i[lo]*t89r[h0];
            float re0 = Lr*prr0 - Li*pii0, im0 = Lr*pii0 + Li*prr0;
            float prr1 = t67r[lo]*t89r[h1] - t67i[lo]*t89i[h1];
            float pii1 = t67r[lo]*t89i[h1] + t67i[lo]*t89r[h1];
            float re1 = Lr*prr1 - Li*pii1, im1 = Lr*pii1 + Li*prr1;
            pr[p] = __builtin_bit_cast(u32, __floats2half2_rn(re0, re1));
            pi[p] = __builtin_bit_cast(u32, __floats2half2_rn(im0, im1));
        }
    }

    const int  baddr = ((lane ^ (lane << 1)) & 63) << 2;
    const bool lpar  = __builtin_popcount(lane & 63) & 1;
    const u32* WH = reinterpret_cast<const u32*>(ws) + 480;

    // ---- layers: chain(l) then gates(l+1), l = 0..4 (last chain folded) ----
    #pragma unroll 1
    for (int l = 0; l < 5; ++l) {
        chainH(pr, baddr, lpar);
        chainH(pi, baddr, lpar);
        const u32* Ub = WH + l * 80;
        lane_gateH<0>(pr, pi, Ub +  0, lane);
        lane_gateH<1>(pr, pi, Ub +  8, lane);
        lane_gateH<2>(pr, pi, Ub + 16, lane);
        lane_gateH<3>(pr, pi, Ub + 24, lane);
        lane_gateH<4>(pr, pi, Ub + 32, lane);
        lane_gateS5H (pr, pi, Ub + 40, lane);
        reg_gateH<1> (pr, pi, Ub + 48);   // qubit 6
        reg_gateH<2> (pr, pi, Ub + 56);   // qubit 7
        reg_gateH<4> (pr, pi, Ub + 64);   // qubit 8
        q9_gateH     (pr, pi, Ub + 72);   // qubit 9
    }

    // ---- readout: extract |amp|^2 to f32, prefix-parity trees --------------
    float P[16];
    #pragma unroll
    for (int p = 0; p < 8; p++) {
        h2 a = b2h(pr[p]), b = b2h(pi[p]);
        float arl = __low2float(a),  ail = __low2float(b);
        float arh = __high2float(a), aih = __high2float(b);
        P[p]     = arl*arl + ail*ail;
        P[p + 8] = arh*arh + aih*aih;
    }
    float u[8], d[8];
    #pragma unroll
    for (int k = 0; k < 8; k++) { u[k] = P[2*k] + P[2*k+1]; d[k] = P[2*k] - P[2*k+1]; }
    float S  = ((u[0]+u[1]) + (u[2]+u[3])) + ((u[4]+u[5]) + (u[6]+u[7]));
    float T0 = ((d[0]+d[1]) + (d[2]+d[3])) + ((d[4]+d[5]) + (d[6]+d[7]));
    float e0 = d[0]-d[1], e1 = d[2]-d[3], e2 = d[4]-d[5], e3 = d[6]-d[7];
    float T1 = (e0+e1) + (e2+e3);
    float f0 = e0-e1, f1 = e2-e3;
    float T2 = f0 + f1;
    float T3 = f0 - f1;

    float z[10];
    z[0] = z_mixed<0>(S, lane);
    z[1] = z_mixed<1>(S, lane);
    z[2] = z_mixed<2>(S, lane);
    z[3] = z_mixed<3>(S, lane);
    z[4] = z_mixed<4>(S, lane);
    z[5] = z_mixed<5>(S, lane);
    z[6] = z_mixed<5>(T0, lane);
    z[7] = z_mixed<5>(T1, lane);
    z[8] = z_mixed<5>(T2, lane);
    z[9] = z_mixed<5>(T3, lane);

    // ---- tail MLP: z -> relu(16) -> 2 (redundant per lane, lane0 stores) ---
    float acc0 = b4[0], acc1 = b4[1];
    #pragma unroll
    for (int j2 = 0; j2 < 16; j2++) {
        float a = b3[j2];
        #pragma unroll
        for (int q = 0; q < 10; q++) a = fmaf(W3[j2*10 + q], z[q], a);
        a = fmaxf(a, 0.0f);
        acc0 = fmaf(W4[j2],      a, acc0);
        acc1 = fmaf(W4[16 + j2], a, acc1);
    }
    if (lane == 0) {
        reinterpret_cast<float2*>(out)[s] = make_float2(acc0, acc1);
    }
}

extern "C" void kernel_launch(void* const* d_in, const int* in_sizes, int n_in,
                              void* d_out, int out_size, void* d_ws, size_t ws_size,
                              hipStream_t stream)
{
    (void)in_sizes; (void)n_in; (void)out_size; (void)ws_size;
    const float* x  = (const float*)d_in[0];
    const float* W1 = (const float*)d_in[1];
    const float* b1 = (const float*)d_in[2];
    const float* W2 = (const float*)d_in[3];
    const float* b2 = (const float*)d_in[4];
    const float* qp = (const float*)d_in[5];
    const float* W3 = (const float*)d_in[6];
    const float* b3 = (const float*)d_in[7];
    const float* W4 = (const float*)d_in[8];
    const float* b4 = (const float*)d_in[9];
    float* ws  = (float*)d_ws;
    float* out = (float*)d_out;

    k_prep<<<1, 64, 0, stream>>>(qp, ws);
    k_qsim<<<4096, 256, 0, stream>>>(x, W1, b1, W2, b2, ws, W3, b3, W4, b4, out);
}